// Round 6
// baseline (526.183 us; speedup 1.0000x reference)
//
#include <hip/hip_runtime.h>
#include <hip/hip_bf16.h>

#define B_ 4
#define L_ 4096
#define D_ 1024
#define H_ 2048
#define M_ (B_*L_)          // 16384 rows
#define NCHUNK 64
#define TCHUNK 64           // NCHUNK*TCHUNK == L_

typedef __attribute__((ext_vector_type(8))) short short8;
typedef __attribute__((ext_vector_type(4))) float floatx4;

__device__ __forceinline__ ushort f2bf(float f){
  uint u = __float_as_uint(f);
  u += 0x7FFFu + ((u >> 16) & 1u);          // RNE
  return (ushort)(u >> 16);
}
__device__ __forceinline__ float bf2f(ushort s){
  return __uint_as_float(((uint)s) << 16);
}

// ---------------- converts ----------------
// XCD-affine: block (bid&7) converts xb rows [xcd*2048, xcd*2048+2048) so the
// gemm1 blocks on that XCD find their A-panels in the local L2 (4MB = L2 size).
__global__ void cvt_f32_bf16(const float4* __restrict__ in, ushort4* __restrict__ out){
  const int bid  = blockIdx.x;                   // 2048 blocks x 256 thr
  const int base = (bid & 7) * 524288 + (bid >> 3) * 256 + threadIdx.x;
  #pragma unroll
  for (int it = 0; it < 8; it++){
    int i = base + it * 65536;
    float4 v = in[i];
    ushort4 o;
    o.x = f2bf(v.x); o.y = f2bf(v.y); o.z = f2bf(v.z); o.w = f2bf(v.w);
    out[i] = o;
  }
}

// fused weight transposes: z=0 Wf->WfiT(f-slot), z=1 Wi->WfiT(i-slot), z=2 Wo->WoT
// in [R][C] f32 -> out [orow(C)][R] bf16
__global__ void transpose_cvt_all(const float* __restrict__ Wf, const float* __restrict__ Wi,
                                  const float* __restrict__ Wo, ushort* __restrict__ WfiT,
                                  ushort* __restrict__ WoT){
  __shared__ float tile[32][33];
  const int z = blockIdx.z;
  const float* in = (z == 0) ? Wf : (z == 1) ? Wi : Wo;
  ushort* out = (z == 2) ? WoT : WfiT;
  const int R = (z == 2) ? H_ : D_;
  const int C = (z == 2) ? D_ : H_;
  const int bx = (z == 2) ? blockIdx.y : blockIdx.x;   // C/32 tiles
  const int by = (z == 2) ? blockIdx.x : blockIdx.y;   // R/32 tiles
  const int c0 = bx * 32, r0 = by * 32;
  const int tx = threadIdx.x, ty = threadIdx.y;        // (32,8)
  #pragma unroll
  for (int i = 0; i < 4; i++){
    int r = r0 + ty + i*8;
    tile[ty + i*8][tx] = in[(size_t)r*C + c0 + tx];
  }
  __syncthreads();
  #pragma unroll
  for (int i = 0; i < 4; i++){
    int c = c0 + ty + i*8;
    int orow = (z == 2) ? c : (((c >> 4) << 5) + ((z == 1) ? 16 : 0) + (c & 15));
    out[(size_t)orow*R + r0 + tx] = f2bf(tile[tx][ty + i*8]);
  }
}

// ---------------- unified GEMM (m97 structure + chunk XOR swizzle) ----------------
// A [M][K] bf16 row-major; Bm [N][K] bf16 (B^T layout)
// EPI 0: out = float* y, y = acc + b0[col]
// EPI 1: out = uint* rz (packed r,z bf16x2) + per-chunk scan summaries Ac,Bc
// Block mapping: XCD-chunked 4x4 patches; xcd = m_row/2048 (affinity chain key).
template<int K, int N, int NBN, int EPI>
__global__ __launch_bounds__(256, 5) void gemm_bt(
    const ushort* __restrict__ A,
    const ushort* __restrict__ Bm,
    const float*  __restrict__ b0,
    const float*  __restrict__ b1,
    void*         __restrict__ outp,
    float*        __restrict__ Ac,
    float*        __restrict__ Bc)
{
  __shared__ ushort As[128*64];
  __shared__ ushort Bs[128*64];

  const int tid  = threadIdx.x;
  const int lane = tid & 63;
  const int wid  = tid >> 6;
  const int wr = wid >> 1, wc = wid & 1;
  const int l15 = lane & 15;
  const int l4  = lane >> 4;

  // XCD patch mapping (bijective: 8 xcds x (4 x NBN/4 patches) x 16 blocks)
  constexpr int PN = NBN / 4;
  const int bid   = blockIdx.x;
  const int xcd   = bid & 7;
  const int local = bid >> 3;
  const int P = local >> 4;
  const int w = local & 15;
  const int pm = P / PN, pn = P % PN;
  const int bm = xcd*16 + pm*4 + (w >> 2);
  const int bn = pn*4 + (w & 3);
  const int tm = bm * 128;
  const int tn = bn * 128;

  floatx4 acc[4][4];
  #pragma unroll
  for (int m = 0; m < 4; m++)
    #pragma unroll
    for (int n = 0; n < 4; n++) acc[m][n] = (floatx4)(0.f);

  for (int k0 = 0; k0 < K; k0 += 64){
    const ushort* Ab = A  + (size_t)tm*K + k0;
    const ushort* Bb = Bm + (size_t)tn*K + k0;
    #pragma unroll
    for (int i = 0; i < 4; i++){
      int idx = i*256 + tid;                    // 16B chunk id, 1024 chunks = 16KB
      int row = idx >> 3;                       // 8 chunks per 128B row
      int ce  = (((idx & 7) ^ (row & 7)) * 8);  // swizzled source element offset
      __builtin_amdgcn_global_load_lds((const __attribute__((address_space(1))) void*)(Ab + (size_t)row*K + ce),
                                       (__attribute__((address_space(3))) void*)(As + idx*8), 16, 0, 0);
      __builtin_amdgcn_global_load_lds((const __attribute__((address_space(1))) void*)(Bb + (size_t)row*K + ce),
                                       (__attribute__((address_space(3))) void*)(Bs + idx*8), 16, 0, 0);
    }
    __syncthreads();
    #pragma unroll
    for (int kk = 0; kk < 64; kk += 32){
      short8 af[4], bf_[4];
      #pragma unroll
      for (int m = 0; m < 4; m++){
        int row = wr*64 + m*16 + l15;
        int c   = (kk >> 3) + l4;               // chunk 0..7
        af[m] = *(const short8*)(As + row*64 + ((c ^ (row & 7)) * 8));
      }
      #pragma unroll
      for (int n = 0; n < 4; n++){
        int row = wc*64 + n*16 + l15;
        int c   = (kk >> 3) + l4;
        bf_[n] = *(const short8*)(Bs + row*64 + ((c ^ (row & 7)) * 8));
      }
      #pragma unroll
      for (int m = 0; m < 4; m++)
        #pragma unroll
        for (int n = 0; n < 4; n++)
          acc[m][n] = __builtin_amdgcn_mfma_f32_16x16x32_bf16(af[m], bf_[n], acc[m][n], 0, 0, 0);
    }
    __syncthreads();
  }

  if (EPI == 0){
    float* y = (float*)outp;
    #pragma unroll
    for (int n = 0; n < 4; n++){
      int col = tn + wc*64 + n*16 + l15;
      float bv = b0[col];
      #pragma unroll
      for (int m = 0; m < 4; m++){
        int row0 = tm + wr*64 + m*16 + l4*4;
        #pragma unroll
        for (int r = 0; r < 4; r++)
          y[(size_t)(row0 + r)*N + col] = acc[m][n][r] + bv;
      }
    }
  } else {
    // interleaved cols: frag n (even) = f-preact, frag n+1 = i-preact, same h set.
    // Also compute this wave's 64-t chunk scan summary (A=prod a, B) per h.
    uint* rz = (uint*)outp;
    const int rowbase = tm + wr*64;             // wave's chunk start (global M row)
    const int bidx  = rowbase >> 12;            // / L_
    const int chunk = (rowbase >> 6) & (NCHUNK-1);
    #pragma unroll
    for (int p = 0; p < 2; p++){
      int n = p*2;
      int h = ((tn + wc*64 + n*16) >> 1) + l15;
      float bfc = b0[h], bic = b1[h];
      float lin = (float)h * (1.0f / (float)(H_-1));
      float Am = 1.f, Bmv = 0.f;                // running chunk composition (t-order)
      #pragma unroll
      for (int m = 0; m < 4; m++){
        int row0 = tm + wr*64 + m*16 + l4*4;
        float As_ = 1.f, Bs_ = 0.f;             // thread-local 4-t segment
        #pragma unroll
        for (int r = 0; r < 4; r++){
          float pf = acc[m][n][r]   + bfc;
          float pi = acc[m][n+1][r] + bic;
          float rem = lin / (1.0f + __expf(-pf));
          float z   = rem * tanhf(pi);
          rz[(size_t)(row0 + r)*H_ + h] = (uint)f2bf(rem) | ((uint)f2bf(z) << 16);
          float a = 1.f - rem;
          As_ *= a;
          Bs_ = fmaf(a, Bs_, z);
        }
        // butterfly across l4 (lane bits 4,5), order-aware (non-commutative)
        #pragma unroll
        for (int s = 16; s <= 32; s <<= 1){
          float Ao = __shfl_xor(As_, s, 64);
          float Bo = __shfl_xor(Bs_, s, 64);
          if (lane & s){ Bs_ = fmaf(As_, Bo, Bs_); }   // partner earlier
          else         { Bs_ = fmaf(Ao, Bs_, Bo); }    // mine earlier
          As_ *= Ao;
        }
        // append segment m
        Bmv = fmaf(As_, Bmv, Bs_);
        Am  *= As_;
      }
      if ((lane & 48) == 0){                    // l4 == 0: one writer per h
        size_t o = ((size_t)(bidx*NCHUNK + chunk))*H_ + h;
        Ac[o] = Am; Bc[o] = Bmv;
      }
    }
  }
}

// ---------------- scan ----------------
__global__ void scan_passB(const float* __restrict__ Ac, const float* __restrict__ Bc,
                           const float* __restrict__ hidden, float* __restrict__ hst,
                           float* __restrict__ hlast){
  int idx = blockIdx.x * blockDim.x + threadIdx.x;  // B_*H_ threads
  int h = idx & (H_-1);
  int b = idx >> 11;
  float run = hidden[idx];
  for (int c = 0; c < NCHUNK; c++){
    size_t o = ((size_t)(b*NCHUNK + c))*H_ + h;
    hst[o] = run;
    run = fmaf(Ac[o], run, Bc[o]);
  }
  hlast[idx] = run;
}

// 2 h-channels per thread (uint2 loads, packed uint stores).
// XCD-affine: xcd = m_row/2048 = b*2 + (chunk>=32) matches gemm1 (rz writer)
// and gemm2 (hb reader) block mappings.
__global__ void scan_passC(const uint* __restrict__ rz, const float* __restrict__ hst,
                           ushort* __restrict__ hb){
  const int bid   = blockIdx.x;                // 1024 blocks x 256 thr
  const int xcd   = bid & 7;
  const int local = bid >> 3;                  // 0..127
  const int b     = xcd >> 1;
  const int chunk = (xcd & 1)*32 + (local & 31);
  const int hblk  = local >> 5;                // 0..3
  const int h0    = (hblk*256 + threadIdx.x)*2;

  const size_t rowbase = (size_t)(b*L_ + chunk*TCHUNK);
  float2 hv = *(const float2*)(hst + ((size_t)(b*NCHUNK + chunk))*H_ + h0);
  const uint2* p = (const uint2*)(rz + rowbase*H_ + h0);
  uint*        q = (uint*)(hb + rowbase*H_ + h0);
  #pragma unroll 8
  for (int t = 0; t < TCHUNK; t++){
    uint2 u = p[(size_t)t*(H_/2)];
    float r0 = bf2f((ushort)(u.x & 0xFFFFu)), z0 = bf2f((ushort)(u.x >> 16));
    float r1 = bf2f((ushort)(u.y & 0xFFFFu)), z1 = bf2f((ushort)(u.y >> 16));
    hv.x = fmaf(1.f - r0, hv.x, z0);
    hv.y = fmaf(1.f - r1, hv.y, z1);
    q[(size_t)t*(H_/2)] = (uint)f2bf(hv.x) | ((uint)f2bf(hv.y) << 16);
  }
}

extern "C" void kernel_launch(void* const* d_in, const int* in_sizes, int n_in,
                              void* d_out, int out_size, void* d_ws, size_t ws_size,
                              hipStream_t stream)
{
  const float* x      = (const float*)d_in[0];
  const float* hidden = (const float*)d_in[1];
  const float* Wf     = (const float*)d_in[2];
  const float* bf     = (const float*)d_in[3];
  const float* Wi     = (const float*)d_in[4];
  const float* bi     = (const float*)d_in[5];
  const float* Wo     = (const float*)d_in[6];
  const float* bo     = (const float*)d_in[7];

  float* y     = (float*)d_out;                 // [M_][D_]
  float* hlast = y + (size_t)M_*D_;             // [B_][H_]

  char* ws = (char*)d_ws;
  ushort* xb   = (ushort*)ws;  ws += (size_t)M_*D_*2;
  ushort* WfiT = (ushort*)ws;  ws += (size_t)(2*H_)*D_*2;   // [4096][1024] interleaved
  ushort* WoT  = (ushort*)ws;  ws += (size_t)D_*H_*2;
  uint*   rz   = (uint*)ws;    ws += (size_t)M_*H_*4;
  ushort* hb   = (ushort*)ws;  ws += (size_t)M_*H_*2;
  float*  Ac   = (float*)ws;   ws += (size_t)B_*NCHUNK*H_*4;
  float*  Bc   = (float*)ws;   ws += (size_t)B_*NCHUNK*H_*4;
  float*  hst  = (float*)ws;   ws += (size_t)B_*NCHUNK*H_*4;

  cvt_f32_bf16<<<2048, 256, 0, stream>>>((const float4*)x, (ushort4*)xb);
  transpose_cvt_all<<<dim3(H_/32, D_/32, 3), dim3(32,8), 0, stream>>>(Wf, Wi, Wo, WfiT, WoT);

  // gemm1: [16384][1024] @ [4096][1024]^T -> rz + chunk summaries (4096 blocks)
  gemm_bt<D_, 2*H_, 32, 1><<<4096, 256, 0, stream>>>(xb, WfiT, bf, bi, rz, Ac, Bc);

  scan_passB<<<(B_*H_)/256, 256, 0, stream>>>(Ac, Bc, hidden, hst, hlast);
  scan_passC<<<1024, 256, 0, stream>>>(rz, hst, hb);

  // gemm2: [16384][2048] @ [1024][2048]^T -> y (1024 blocks)
  gemm_bt<H_, D_, 8, 0><<<1024, 256, 0, stream>>>(hb, WoT, bo, nullptr, y, nullptr, nullptr);
}

// Round 7
// 302.966 us; speedup vs baseline: 1.7368x; 1.7368x over previous
//
#include <hip/hip_runtime.h>
#include <hip/hip_bf16.h>

#define B_ 4
#define L_ 4096
#define D_ 1024
#define H_ 2048
#define M_ (B_*L_)          // 16384 rows
#define NCHUNK 64
#define TCHUNK 64           // NCHUNK*TCHUNK == L_

typedef __attribute__((ext_vector_type(8))) short short8;
typedef __attribute__((ext_vector_type(4))) float floatx4;

__device__ __forceinline__ ushort f2bf(float f){
  uint u = __float_as_uint(f);
  u += 0x7FFFu + ((u >> 16) & 1u);          // RNE
  return (ushort)(u >> 16);
}
__device__ __forceinline__ float bf2f(ushort s){
  return __uint_as_float(((uint)s) << 16);
}

// ---------------- converts ----------------
// XCD-affine: block (bid&7) converts xb rows [xcd*2048, xcd*2048+2048) so the
// gemm1 blocks on that XCD find their A-panels in the local L2 (4MB = L2 size).
__global__ void cvt_f32_bf16(const float4* __restrict__ in, ushort4* __restrict__ out){
  const int bid  = blockIdx.x;                   // 2048 blocks x 256 thr
  const int base = (bid & 7) * 524288 + (bid >> 3) * 256 + threadIdx.x;
  #pragma unroll
  for (int it = 0; it < 8; it++){
    int i = base + it * 65536;
    float4 v = in[i];
    ushort4 o;
    o.x = f2bf(v.x); o.y = f2bf(v.y); o.z = f2bf(v.z); o.w = f2bf(v.w);
    out[i] = o;
  }
}

// fused weight transposes: z=0 Wf->WfiT(f-slot), z=1 Wi->WfiT(i-slot), z=2 Wo->WoT
// in [R][C] f32 -> out [orow(C)][R] bf16
__global__ void transpose_cvt_all(const float* __restrict__ Wf, const float* __restrict__ Wi,
                                  const float* __restrict__ Wo, ushort* __restrict__ WfiT,
                                  ushort* __restrict__ WoT){
  __shared__ float tile[32][33];
  const int z = blockIdx.z;
  const float* in = (z == 0) ? Wf : (z == 1) ? Wi : Wo;
  ushort* out = (z == 2) ? WoT : WfiT;
  const int R = (z == 2) ? H_ : D_;
  const int C = (z == 2) ? D_ : H_;
  const int bx = (z == 2) ? blockIdx.y : blockIdx.x;   // C/32 tiles
  const int by = (z == 2) ? blockIdx.x : blockIdx.y;   // R/32 tiles
  const int c0 = bx * 32, r0 = by * 32;
  const int tx = threadIdx.x, ty = threadIdx.y;        // (32,8)
  #pragma unroll
  for (int i = 0; i < 4; i++){
    int r = r0 + ty + i*8;
    tile[ty + i*8][tx] = in[(size_t)r*C + c0 + tx];
  }
  __syncthreads();
  #pragma unroll
  for (int i = 0; i < 4; i++){
    int c = c0 + ty + i*8;
    int orow = (z == 2) ? c : (((c >> 4) << 5) + ((z == 1) ? 16 : 0) + (c & 15));
    out[(size_t)orow*R + r0 + tx] = f2bf(tile[tx][ty + i*8]);
  }
}

// ---------------- unified GEMM (m97 structure + chunk XOR swizzle) ----------------
// A [M][K] bf16 row-major; Bm [N][K] bf16 (B^T layout)
// EPI 0: out = float* y, y = acc + b0[col]
// EPI 1: out = uint* rz (packed r,z bf16x2) + per-chunk scan summaries Ac,Bc
// Block mapping: XCD-chunked 4x4 patches; xcd = m_row/2048 (affinity chain key).
// NOTE: __launch_bounds__(256,4) ONLY — (256,5) caps VGPR<64 and spills the
// 64-reg accumulator to scratch (round-6 regression: +150MB write, MfmaUtil 17%).
template<int K, int N, int NBN, int EPI>
__global__ __launch_bounds__(256, 4) void gemm_bt(
    const ushort* __restrict__ A,
    const ushort* __restrict__ Bm,
    const float*  __restrict__ b0,
    const float*  __restrict__ b1,
    void*         __restrict__ outp,
    float*        __restrict__ Ac,
    float*        __restrict__ Bc)
{
  __shared__ ushort As[128*64];
  __shared__ ushort Bs[128*64];

  const int tid  = threadIdx.x;
  const int lane = tid & 63;
  const int wid  = tid >> 6;
  const int wr = wid >> 1, wc = wid & 1;
  const int l15 = lane & 15;
  const int l4  = lane >> 4;

  // XCD patch mapping (bijective: 8 xcds x (4 x NBN/4 patches) x 16 blocks)
  constexpr int PN = NBN / 4;
  const int bid   = blockIdx.x;
  const int xcd   = bid & 7;
  const int local = bid >> 3;
  const int P = local >> 4;
  const int w = local & 15;
  const int pm = P / PN, pn = P % PN;
  const int bm = xcd*16 + pm*4 + (w >> 2);
  const int bn = pn*4 + (w & 3);
  const int tm = bm * 128;
  const int tn = bn * 128;

  floatx4 acc[4][4];
  #pragma unroll
  for (int m = 0; m < 4; m++)
    #pragma unroll
    for (int n = 0; n < 4; n++) acc[m][n] = (floatx4)(0.f);

  for (int k0 = 0; k0 < K; k0 += 64){
    const ushort* Ab = A  + (size_t)tm*K + k0;
    const ushort* Bb = Bm + (size_t)tn*K + k0;
    #pragma unroll
    for (int i = 0; i < 4; i++){
      int idx = i*256 + tid;                    // 16B chunk id, 1024 chunks = 16KB
      int row = idx >> 3;                       // 8 chunks per 128B row
      int ce  = (((idx & 7) ^ (row & 7)) * 8);  // swizzled source element offset
      __builtin_amdgcn_global_load_lds((const __attribute__((address_space(1))) void*)(Ab + (size_t)row*K + ce),
                                       (__attribute__((address_space(3))) void*)(As + idx*8), 16, 0, 0);
      __builtin_amdgcn_global_load_lds((const __attribute__((address_space(1))) void*)(Bb + (size_t)row*K + ce),
                                       (__attribute__((address_space(3))) void*)(Bs + idx*8), 16, 0, 0);
    }
    __syncthreads();
    #pragma unroll
    for (int kk = 0; kk < 64; kk += 32){
      short8 af[4], bf_[4];
      #pragma unroll
      for (int m = 0; m < 4; m++){
        int row = wr*64 + m*16 + l15;
        int c   = (kk >> 3) + l4;               // chunk 0..7
        af[m] = *(const short8*)(As + row*64 + ((c ^ (row & 7)) * 8));
      }
      #pragma unroll
      for (int n = 0; n < 4; n++){
        int row = wc*64 + n*16 + l15;
        int c   = (kk >> 3) + l4;
        bf_[n] = *(const short8*)(Bs + row*64 + ((c ^ (row & 7)) * 8));
      }
      #pragma unroll
      for (int m = 0; m < 4; m++)
        #pragma unroll
        for (int n = 0; n < 4; n++)
          acc[m][n] = __builtin_amdgcn_mfma_f32_16x16x32_bf16(af[m], bf_[n], acc[m][n], 0, 0, 0);
    }
    __syncthreads();
  }

  if (EPI == 0){
    float* y = (float*)outp;
    #pragma unroll
    for (int n = 0; n < 4; n++){
      int col = tn + wc*64 + n*16 + l15;
      float bv = b0[col];
      #pragma unroll
      for (int m = 0; m < 4; m++){
        int row0 = tm + wr*64 + m*16 + l4*4;
        #pragma unroll
        for (int r = 0; r < 4; r++)
          y[(size_t)(row0 + r)*N + col] = acc[m][n][r] + bv;
      }
    }
  } else {
    // interleaved cols: frag n (even) = f-preact, frag n+1 = i-preact, same h set.
    // Also compute this wave's 64-t chunk scan summary (A=prod a, B) per h.
    uint* rz = (uint*)outp;
    const int rowbase = tm + wr*64;             // wave's chunk start (global M row)
    const int bidx  = rowbase >> 12;            // / L_
    const int chunk = (rowbase >> 6) & (NCHUNK-1);
    #pragma unroll
    for (int p = 0; p < 2; p++){
      int n = p*2;
      int h = ((tn + wc*64 + n*16) >> 1) + l15;
      float bfc = b0[h], bic = b1[h];
      float lin = (float)h * (1.0f / (float)(H_-1));
      float Am = 1.f, Bmv = 0.f;                // running chunk composition (t-order)
      #pragma unroll
      for (int m = 0; m < 4; m++){
        int row0 = tm + wr*64 + m*16 + l4*4;
        float As_ = 1.f, Bs_ = 0.f;             // thread-local 4-t segment
        #pragma unroll
        for (int r = 0; r < 4; r++){
          float pf = acc[m][n][r]   + bfc;
          float pi = acc[m][n+1][r] + bic;
          float rem = lin / (1.0f + __expf(-pf));
          float z   = rem * tanhf(pi);
          rz[(size_t)(row0 + r)*H_ + h] = (uint)f2bf(rem) | ((uint)f2bf(z) << 16);
          float a = 1.f - rem;
          As_ *= a;
          Bs_ = fmaf(a, Bs_, z);
        }
        // butterfly across l4 (lane bits 4,5), order-aware (non-commutative)
        #pragma unroll
        for (int s = 16; s <= 32; s <<= 1){
          float Ao = __shfl_xor(As_, s, 64);
          float Bo = __shfl_xor(Bs_, s, 64);
          if (lane & s){ Bs_ = fmaf(As_, Bo, Bs_); }   // partner earlier
          else         { Bs_ = fmaf(Ao, Bs_, Bo); }    // mine earlier
          As_ *= Ao;
        }
        // append segment m
        Bmv = fmaf(As_, Bmv, Bs_);
        Am  *= As_;
      }
      if ((lane & 48) == 0){                    // l4 == 0: one writer per h
        size_t o = ((size_t)(bidx*NCHUNK + chunk))*H_ + h;
        Ac[o] = Am; Bc[o] = Bmv;
      }
    }
  }
}

// ---------------- scan ----------------
__global__ void scan_passB(const float* __restrict__ Ac, const float* __restrict__ Bc,
                           const float* __restrict__ hidden, float* __restrict__ hst,
                           float* __restrict__ hlast){
  int idx = blockIdx.x * blockDim.x + threadIdx.x;  // B_*H_ threads
  int h = idx & (H_-1);
  int b = idx >> 11;
  float run = hidden[idx];
  for (int c = 0; c < NCHUNK; c++){
    size_t o = ((size_t)(b*NCHUNK + c))*H_ + h;
    hst[o] = run;
    run = fmaf(Ac[o], run, Bc[o]);
  }
  hlast[idx] = run;
}

// 2 h-channels per thread (uint2 loads, packed uint stores).
// XCD-affine: xcd = m_row/2048 = b*2 + (chunk>=32) matches gemm1 (rz writer)
// and gemm2 (hb reader) block mappings.
__global__ void scan_passC(const uint* __restrict__ rz, const float* __restrict__ hst,
                           ushort* __restrict__ hb){
  const int bid   = blockIdx.x;                // 1024 blocks x 256 thr
  const int xcd   = bid & 7;
  const int local = bid >> 3;                  // 0..127
  const int b     = xcd >> 1;
  const int chunk = (xcd & 1)*32 + (local & 31);
  const int hblk  = local >> 5;                // 0..3
  const int h0    = (hblk*256 + threadIdx.x)*2;

  const size_t rowbase = (size_t)(b*L_ + chunk*TCHUNK);
  float2 hv = *(const float2*)(hst + ((size_t)(b*NCHUNK + chunk))*H_ + h0);
  const uint2* p = (const uint2*)(rz + rowbase*H_ + h0);
  uint*        q = (uint*)(hb + rowbase*H_ + h0);
  #pragma unroll 8
  for (int t = 0; t < TCHUNK; t++){
    uint2 u = p[(size_t)t*(H_/2)];
    float r0 = bf2f((ushort)(u.x & 0xFFFFu)), z0 = bf2f((ushort)(u.x >> 16));
    float r1 = bf2f((ushort)(u.y & 0xFFFFu)), z1 = bf2f((ushort)(u.y >> 16));
    hv.x = fmaf(1.f - r0, hv.x, z0);
    hv.y = fmaf(1.f - r1, hv.y, z1);
    q[(size_t)t*(H_/2)] = (uint)f2bf(hv.x) | ((uint)f2bf(hv.y) << 16);
  }
}

extern "C" void kernel_launch(void* const* d_in, const int* in_sizes, int n_in,
                              void* d_out, int out_size, void* d_ws, size_t ws_size,
                              hipStream_t stream)
{
  const float* x      = (const float*)d_in[0];
  const float* hidden = (const float*)d_in[1];
  const float* Wf     = (const float*)d_in[2];
  const float* bf     = (const float*)d_in[3];
  const float* Wi     = (const float*)d_in[4];
  const float* bi     = (const float*)d_in[5];
  const float* Wo     = (const float*)d_in[6];
  const float* bo     = (const float*)d_in[7];

  float* y     = (float*)d_out;                 // [M_][D_]
  float* hlast = y + (size_t)M_*D_;             // [B_][H_]

  char* ws = (char*)d_ws;
  ushort* xb   = (ushort*)ws;  ws += (size_t)M_*D_*2;
  ushort* WfiT = (ushort*)ws;  ws += (size_t)(2*H_)*D_*2;   // [4096][1024] interleaved
  ushort* WoT  = (ushort*)ws;  ws += (size_t)D_*H_*2;
  uint*   rz   = (uint*)ws;    ws += (size_t)M_*H_*4;
  ushort* hb   = (ushort*)ws;  ws += (size_t)M_*H_*2;
  float*  Ac   = (float*)ws;   ws += (size_t)B_*NCHUNK*H_*4;
  float*  Bc   = (float*)ws;   ws += (size_t)B_*NCHUNK*H_*4;
  float*  hst  = (float*)ws;   ws += (size_t)B_*NCHUNK*H_*4;

  cvt_f32_bf16<<<2048, 256, 0, stream>>>((const float4*)x, (ushort4*)xb);
  transpose_cvt_all<<<dim3(H_/32, D_/32, 3), dim3(32,8), 0, stream>>>(Wf, Wi, Wo, WfiT, WoT);

  // gemm1: [16384][1024] @ [4096][1024]^T -> rz + chunk summaries (4096 blocks)
  gemm_bt<D_, 2*H_, 32, 1><<<4096, 256, 0, stream>>>(xb, WfiT, bf, bi, rz, Ac, Bc);

  scan_passB<<<(B_*H_)/256, 256, 0, stream>>>(Ac, Bc, hidden, hst, hlast);
  scan_passC<<<1024, 256, 0, stream>>>(rz, hst, hb);

  // gemm2: [16384][2048] @ [1024][2048]^T -> y (1024 blocks)
  gemm_bt<H_, D_, 8, 0><<<1024, 256, 0, stream>>>(hb, WoT, bo, nullptr, y, nullptr, nullptr);
}